// Round 3
// baseline (1073.719 us; speedup 1.0000x reference)
//
#include <hip/hip_runtime.h>

// ===================== CALIBRATION ROUND =====================
// Purpose: isolate the spa kernel's standalone time, which has never been
// directly observed (it never makes the rocprof top-5; all we know is
// T_kernel < 316 us). Three structurally different gather engines (R0 reg
// pipeline, R1 high-occupancy, R2 DMA ring) all landed at 609-615 us total,
// which is consistent BOTH with "kernel ~290us, hard memory-system bound"
// AND "kernel ~50us, harness floor ~560us". These imply opposite actions.
//
// Method: launch the identical R2 kernel 9x in the captured graph (kernel
// is idempotent: out is a pure function of read-only inputs, so correctness
// is unchanged). T_kernel = (dur_us - 613) / 8. Later launches may run
// L3-warm; per-dispatch counters (if kernels reach top-5) give the
// cold-vs-warm split, which is itself actionable locality information.
// The best kernel (single launch) is trivially restored afterwards.
// =============================================================

#define BATCH 16384
#define KNB   32
#define FDIM  128
#define EDIM  128
#define ROWS_PER_BLOCK 8
#define DEPTH 8        // DMA ring slots per wave (1KB each)
#define IDX_PITCH 33
#define A_PITCH  132

__global__ __launch_bounds__(256, 4)
void spa_agg_kernel(const float* __restrict__ id2feat,
                    const float* __restrict__ weight,
                    const float* __restrict__ bias,
                    const int* __restrict__ neigh_idx,
                    float* __restrict__ out) {
    __shared__ float4 stage[4][DEPTH][64];             // 32 KB DMA landing ring
    __shared__ float  sA[ROWS_PER_BLOCK * A_PITCH];    // ~4.2 KB
    __shared__ int    sIdx[ROWS_PER_BLOCK * IDX_PITCH];// ~1.1 KB

    const int tid  = threadIdx.x;
    const int lane = tid & 63;
    const int wv   = __builtin_amdgcn_readfirstlane(tid >> 6); // wave id, SGPR
    const int half = lane >> 5;    // 0: row 2w, 1: row 2w+1
    const int lr   = lane & 31;    // 16B chunk within the 512B row
    const int b0   = blockIdx.x * ROWS_PER_BLOCK;

    // ---- phase 1: stage neighbor indices (256 = blockDim, coalesced) ----
    sIdx[(tid >> 5) * IDX_PITCH + (tid & 31)] = neigh_idx[b0 * KNB + tid];
    __syncthreads();

    // preload this lane's 32 indices to registers (static indexing only)
    int myidx[KNB];
    {
        const int* ip = &sIdx[(2 * wv + half) * IDX_PITCH];
        #pragma unroll
        for (int k = 0; k < KNB; ++k) myidx[k] = ip[k];
    }

    // ---- phase 2: DMA gather + average ----
    float4* const mybuf = &stage[wv][0][0];      // wave-uniform LDS base
    const float* gsrc = id2feat + lr * 4;        // +16B chunk per lane

    #define WAITV(N) asm volatile("s_waitcnt vmcnt(" #N ")" ::: "memory")
    #define WAITL    asm volatile("s_waitcnt lgkmcnt(0)" ::: "memory")

    // prologue: fill the ring (8 x 1KB in flight)
    #pragma unroll
    for (int s = 0; s < DEPTH; ++s) {
        __builtin_amdgcn_global_load_lds(
            (const void*)(gsrc + (size_t)myidx[s] * FDIM),
            (void*)(mybuf + s * 64), 16, 0, 0);
    }

    float a0 = 0.f, a1 = 0.f, a2 = 0.f, a3 = 0.f;
    #define ACCUM(K) { const float4 v = mybuf[((K) & (DEPTH - 1)) * 64 + lane]; \
                       a0 += v.x; a1 += v.y; a2 += v.z; a3 += v.w; }

    // steady state: wait oldest slot, consume, refill same slot.
    #pragma unroll
    for (int k = 0; k < KNB - DEPTH; ++k) {      // k = 0..23, fully unrolled
        WAITV(7);
        ACCUM(k);
        WAITL;  // ds_read retired before DMA may overwrite the slot
        __builtin_amdgcn_global_load_lds(
            (const void*)(gsrc + (size_t)myidx[k + DEPTH] * FDIM),
            (void*)(mybuf + (k & (DEPTH - 1)) * 64), 16, 0, 0);
    }
    // epilogue: drain 8 -> 0
    WAITV(7); ACCUM(24);
    WAITV(6); ACCUM(25);
    WAITV(5); ACCUM(26);
    WAITV(4); ACCUM(27);
    WAITV(3); ACCUM(28);
    WAITV(2); ACCUM(29);
    WAITV(1); ACCUM(30);
    WAITV(0); ACCUM(31);

    *(float4*)&sA[(2 * wv + half) * A_PITCH + lr * 4] =
        make_float4(a0 * (1.f / 32.f), a1 * (1.f / 32.f),
                    a2 * (1.f / 32.f), a3 * (1.f / 32.f));
    __syncthreads();

    // ---- phase 3: out[b0+lb][e0..e0+4) = sA[lb] . W[:, e0..e0+4) + bias ----
    {
        const int lb = tid >> 5;
        const int e0 = (tid & 31) * 4;
        float4 acc = *(const float4*)(bias + e0);
        const float* arow = &sA[lb * A_PITCH];
        #pragma unroll 8
        for (int f = 0; f < FDIM; ++f) {
            const float a  = arow[f];                          // LDS broadcast
            const float4 w4 = *(const float4*)(weight + (size_t)f * EDIM + e0);
            acc.x += a * w4.x; acc.y += a * w4.y;
            acc.z += a * w4.z; acc.w += a * w4.w;
        }
        *(float4*)(out + (size_t)(b0 + lb) * EDIM + e0) = acc;
    }
}

extern "C" void kernel_launch(void* const* d_in, const int* in_sizes, int n_in,
                              void* d_out, int out_size, void* d_ws, size_t ws_size,
                              hipStream_t stream) {
    const float* id2feat = (const float*)d_in[0];  // [N, F] fp32
    const float* weight  = (const float*)d_in[1];  // [F, E] fp32
    const float* bias    = (const float*)d_in[2];  // [E]    fp32
    const int*   neigh   = (const int*)d_in[3];    // [B, K] int32
    float*       outp    = (float*)d_out;          // [B, E] fp32

    dim3 grid(BATCH / ROWS_PER_BLOCK);  // 2048
    dim3 block(256);

    // CALIBRATION: 9 identical idempotent launches.
    // T_kernel = (dur_us - 613) / 8.
    for (int rep = 0; rep < 9; ++rep) {
        spa_agg_kernel<<<grid, block, 0, stream>>>(id2feat, weight, bias, neigh, outp);
    }
}

// Round 4
// 609.718 us; speedup vs baseline: 1.7610x; 1.7610x over previous
//
#include <hip/hip_runtime.h>

// SpaAggregator: out[b] = (mean_k id2feat[idx[b,k]]) @ W + bias
// B=16384, K=32, N=1e6, F=128, E=128. float32 in/out, int32 indices.
//
// mean commutes with the linear map: gather-average first (268 MB random
// 512B-row reads, memory-bound), then a tiny per-block GEMM from LDS.
//
// SESSION FINDINGS (R0-R3):
//  - R3 calibration (9x idempotent launches): T_kernel ~= 57 us warm /
//    ~60-90 us cold. The 609 us bench = ~558 us harness fixed cost (2 GB
//    workspace poison fill at 318 us + restores) + this kernel.
//  - The gather runs at ~4.7 TB/s request-level (74% of achievable copy
//    BW, fully random pattern). Three independent gather structures --
//    (a) this 2-blocks/CU register pipeline, (b) 24-waves/CU shallow,
//    (c) vmcnt-ring global_load_lds DMA with 128 KB/CU in flight by
//    construction -- all land within +-3 us: the gather saturates the
//    shared memory system; concurrency is NOT the limiter.
//  - Addressable headroom <= ~25 us (~4% of bench). Kernel is at the
//    random-gather roofline.
//
// Block = 256 threads handles 16 batch rows:
//   phase 1: stage idx tile + W -> fp32 LDS (interleaved layout so phase-3
//            ds_read_b128 is only 2-way bank aliased = free)
//   phase 2: gather-average 16 rows x 32 neighbors; 16 lanes x 32B cover one
//            512B table row contiguously
//   phase 3: per-thread 1x8 output tile GEMM from LDS, fp32 store.

#define BATCH 16384
#define KNB   32
#define FDIM  128
#define EDIM  128
#define ROWS_PER_BLOCK 16
#define IDX_PITCH 33   // pad: banks differ across lb for sIdx reads
#define A_PITCH  132   // pad: kills 4-way conflict on phase-3 broadcast reads

__global__ __launch_bounds__(256, 2)
void spa_agg_kernel(const float* __restrict__ id2feat,
                    const float* __restrict__ weight,
                    const float* __restrict__ bias,
                    const int* __restrict__ neigh_idx,
                    float* __restrict__ out) {
    __shared__ float sW[FDIM * EDIM];                  // 64 KB, interleaved
    __shared__ float sA[ROWS_PER_BLOCK * A_PITCH];     // ~8.25 KB
    __shared__ int   sIdx[ROWS_PER_BLOCK * IDX_PITCH]; // ~2.1 KB

    const int tid = threadIdx.x;
    const int lb  = tid >> 4;   // 0..15 : local batch row
    const int fg  = tid & 15;   // 0..15 : 8-wide feature/embed chunk
    const int b0  = blockIdx.x * ROWS_PER_BLOCK;

    // ---- phase 1a: stage neighbor indices ----
    {
        const int base = b0 * KNB;
        for (int i = tid; i < ROWS_PER_BLOCK * KNB; i += 256) {
            int r = i >> 5, c = i & 31;  // KNB = 32
            sIdx[r * IDX_PITCH + c] = neigh_idx[base + i];
        }
    }
    // ---- phase 1b: W -> LDS, interleaved layout ----
    // e = eg*8 + half*4 + j  ->  sW[f*128 + half*64 + eg*4 + j]
    // each source float4 (e4 = e/4) maps to a contiguous dest float4:
    //   dst = f*128 + (e4&1)*64 + (e4>>1)*4
    {
        for (int i = tid; i < (FDIM * EDIM) / 4; i += 256) {
            int f = i >> 5, e4 = i & 31;
            const float4 w = *(const float4*)(weight + (size_t)f * EDIM + e4 * 4);
            *(float4*)&sW[f * 128 + (e4 & 1) * 64 + (e4 >> 1) * 4] = w;
        }
    }
    __syncthreads();

    // ---- phase 2: gather + average ----
    // thread (lb, fg) accumulates features [fg*8, fg*8+8) of local row lb.
    // 16 consecutive lanes read one 512B table row contiguously (32B/lane).
    {
        float acc[8];
        #pragma unroll
        for (int j = 0; j < 8; ++j) acc[j] = 0.f;
        const int* ip = &sIdx[lb * IDX_PITCH];
        #pragma unroll 8
        for (int k = 0; k < KNB; ++k) {
            const int row = ip[k];
            const float4* rp = (const float4*)(id2feat + (size_t)row * FDIM + fg * 8);
            const float4 r0 = rp[0];
            const float4 r1 = rp[1];
            acc[0] += r0.x; acc[1] += r0.y; acc[2] += r0.z; acc[3] += r0.w;
            acc[4] += r1.x; acc[5] += r1.y; acc[6] += r1.z; acc[7] += r1.w;
        }
        float* ap = &sA[lb * A_PITCH + fg * 8];
        #pragma unroll
        for (int j = 0; j < 8; ++j) ap[j] = acc[j] * (1.f / 32.f);
    }
    __syncthreads();

    // ---- phase 3: out[b0+lb][e0..e0+8) = sA[lb] . sW[:, e0..e0+8) + bias ----
    {
        const int e0 = fg * 8;
        float acc[8];
        #pragma unroll
        for (int j = 0; j < 8; ++j) acc[j] = bias[e0 + j];
        const float* arow = &sA[lb * A_PITCH];
        #pragma unroll 4
        for (int f = 0; f < FDIM; ++f) {
            const float a   = arow[f];                             // LDS broadcast
            const float4 w0 = *(const float4*)&sW[f * 128 + fg * 4];
            const float4 w1 = *(const float4*)&sW[f * 128 + 64 + fg * 4];
            acc[0] += a * w0.x; acc[1] += a * w0.y;
            acc[2] += a * w0.z; acc[3] += a * w0.w;
            acc[4] += a * w1.x; acc[5] += a * w1.y;
            acc[6] += a * w1.z; acc[7] += a * w1.w;
        }
        float* op = out + (size_t)(b0 + lb) * EDIM + e0;
        *(float4*)op       = make_float4(acc[0], acc[1], acc[2], acc[3]);
        *(float4*)(op + 4) = make_float4(acc[4], acc[5], acc[6], acc[7]);
    }
}

extern "C" void kernel_launch(void* const* d_in, const int* in_sizes, int n_in,
                              void* d_out, int out_size, void* d_ws, size_t ws_size,
                              hipStream_t stream) {
    const float* id2feat = (const float*)d_in[0];  // [N, F] fp32
    const float* weight  = (const float*)d_in[1];  // [F, E] fp32
    const float* bias    = (const float*)d_in[2];  // [E]    fp32
    const int*   neigh   = (const int*)d_in[3];    // [B, K] int32
    float*       outp    = (float*)d_out;          // [B, E] fp32

    dim3 grid(BATCH / ROWS_PER_BLOCK);  // 1024
    dim3 block(256);
    spa_agg_kernel<<<grid, block, 0, stream>>>(id2feat, weight, bias, neigh, outp);
}